// Round 12
// baseline (206.899 us; speedup 1.0000x reference)
//
#include <hip/hip_runtime.h>

// LSTM: B=4096, T=256, I=8, H=32, O=1, fp32 in/out, bf16 MFMA compute.
// R12: TWO FULL TILES INTERLEAVED IN ONE WAVE. 128 blocks x 256 threads
// (4 waves, 1/SIMD); block owns 32 batch rows = 2 independent 16-row tiles.
// Every wave carries BOTH tiles' work each step: tile A's ds_read/MFMA/act
// chain stalls are filled by tile B's issue within the same instruction
// stream — interleave with ZERO sync cost (R7's barrier-locked waves stalled
// in phase; R11's 8-row split paid 2x redundancy). No redundant compute:
// both tiles are real 16-row tiles sharing the weight registers.
// Per tile: wave w owns j-pair (8q + 2w + e) per lane via weight-row perm
//   fr -> n = 32*(fr&3) + 8*(fr>>2) + 2w + e  (weights = MFMA FIRST operand)
// -> accum_e quad = gates (i,f,g,o) at (m=L, j=8q+2w+e); adjacent j -> one
// packed b32 h-write; c/h update in-register. One barrier/step covers both
// tiles. x staged in LDS (bf16) in 64-step chunks -> steady loop is vm-free
// (barrier drains lgkm only). Gate-g rows pre-scaled by 2*log2e (others
// log2e): 5 exp2 + 3 rcp per value.

#define T_LEN   256
#define CH      64    // x chunk timesteps
#define XSTRIDE 130   // shorts per timestep row (16 rows x 8 bf16 + 2 pad)
#define LOG2E   1.4426950408889634f

typedef short bf16x8 __attribute__((ext_vector_type(8)));
typedef float f32x4  __attribute__((ext_vector_type(4)));
typedef unsigned u32x4 __attribute__((ext_vector_type(4)));

static __device__ inline short f2bf_rne(float f) {          // one-time (weights)
    union { float f; unsigned u; } v; v.f = f;
    unsigned u = v.u;
    return (short)((u + 0x7FFFu + ((u >> 16) & 1u)) >> 16);
}
static __device__ inline unsigned pack_bf2(float a, float b) {  // low=a, high=b
    union { float f; unsigned u; } x, y; x.f = a; y.f = b;
    return ((x.u + 0x8000u) >> 16) | ((y.u + 0x8000u) & 0xFFFF0000u);
}
static __device__ inline float bf2f(short s) {
    union { unsigned u; float f; } v;
    v.u = ((unsigned)(unsigned short)s) << 16;
    return v.f;
}

__global__ __launch_bounds__(256) void lstm_kernel(
    const float* __restrict__ x, const float* __restrict__ W_ih,
    const float* __restrict__ W_hh, const float* __restrict__ b_ih,
    const float* __restrict__ b_hh, const float* __restrict__ W_out,
    const float* __restrict__ b_out, float* __restrict__ out)
{
    // x chunks per tile: [tile][t_local(0..63)][row(0..15)][8] bf16   (33.3 KB)
    __shared__ __attribute__((aligned(16))) short xl[2][CH * XSTRIDE];
    // h double buffers per tile: [tile][buf][m(0..15)][k stride 40]    (5.1 KB)
    __shared__ __attribute__((aligned(16))) short h_lds[2][2][16 * 40];

    const int tid  = threadIdx.x;
    const int w    = tid >> 6;         // wave 0..3
    const int lane = tid & 63;
    const int L    = lane & 15;        // batch row within tile / frag row
    const int q    = lane >> 4;        // quad
    const int rbase = blockIdx.x * 32; // block's first batch row (2 tiles)
    const float4* xv = (const float4*)x;

    // ---- one-time: weight fragments (FIRST-operand layout [row=L][k=8q+j]),
    // shared by both tiles. frag e row fr=L holds W row
    // n = 32*(L&3) + 8*(L>>2) + 2w + e, scaled by log2e (gate-g: 2*log2e).
    bf16x8 whh[2], wih[2];
    f32x4  bias[2];
#pragma unroll
    for (int e = 0; e < 2; ++e) {
        const int   n  = 32 * (L & 3) + 8 * (L >> 2) + 2 * w + e;
        const float sc = ((L & 3) == 2 ? 2.f * LOG2E : LOG2E);
        const float* src = W_hh + n * 32 + q * 8;
        bf16x8 fr;
#pragma unroll
        for (int j = 0; j < 8; ++j) fr[j] = f2bf_rne(src[j] * sc);
        whh[e] = fr;
        bf16x8 gr = (bf16x8){0,0,0,0,0,0,0,0};
        if (q == 0) {                              // only k=0..7 exist (I=8)
            const float* s2 = W_ih + n * 8;
#pragma unroll
            for (int j = 0; j < 8; ++j) gr[j] = f2bf_rne(s2[j] * sc);
        }
        wih[e] = gr;
        // bias in C-layout: reg r -> row fr=4q+r -> n_r = 32r + 8q + 2w + e
        f32x4 bb;
#pragma unroll
        for (int r = 0; r < 4; ++r) {
            const int   nr = 32 * r + 8 * q + 2 * w + e;
            const float sr = (r == 2 ? 2.f * LOG2E : LOG2E);
            bb[r] = (b_ih[nr] + b_hh[nr]) * sr;
        }
        bias[e] = bb;
    }

    // zero h(0) buffers (both tiles, both bufs — cheap)
    for (int i = tid; i < 2 * 2 * 16 * 40; i += 256) ((short*)h_lds)[i] = 0;

    // ---- stage chunk 0 (t in [0,64)) for BOTH tiles ----
    // 2 tiles x 64 t x 16 rows = 2048 32B-units, 8 per thread, coalesced.
#pragma unroll
    for (int it = 0; it < 8; ++it) {
        const int idx = tid + (it << 8);
        const int tau = idx >> 10;
        const int rem = idx & 1023;
        const int tl  = rem & (CH - 1);
        const int L2  = rem >> 6;
        const float4* srcp = xv + ((size_t)(rbase + tau * 16 + L2) * T_LEN + tl) * 2;
        const float4 a = srcp[0], b = srcp[1];
        u32x4 u;
        u[0] = pack_bf2(a.x, a.y); u[1] = pack_bf2(a.z, a.w);
        u[2] = pack_bf2(b.x, b.y); u[3] = pack_bf2(b.z, b.w);
        *(u32x4*)(&xl[tau][tl * XSTRIDE + L2 * 8]) = u;
    }
    __syncthreads();

    // zx(0) for both tiles
    f32x4 zx[2][2];
#pragma unroll
    for (int tau = 0; tau < 2; ++tau) {
        const bf16x8 xf0 = *(const bf16x8*)(&xl[tau][L * 8]);
        zx[tau][0] = __builtin_amdgcn_mfma_f32_16x16x32_bf16(wih[0], xf0, bias[0], 0, 0, 0);
        zx[tau][1] = __builtin_amdgcn_mfma_f32_16x16x32_bf16(wih[1], xf0, bias[1], 0, 0, 0);
    }

    float c[2][2] = {{0.f, 0.f}, {0.f, 0.f}};
    const int hwo = L * 40 + 8 * q + 2 * w;        // h-write offset (shorts)
    const int hro = L * 40 + q * 8;                // h-read offset

#pragma unroll 2
    for (int t = 0; t < T_LEN; ++t) {
        if ((t & (CH - 1)) == CH - 1 && t != T_LEN - 1) {
            // restage next chunk for both tiles (prev chunk fully consumed:
            // last read was x(t) during body t-1, before its barrier)
            const int ck = (t >> 6) + 1;
#pragma unroll
            for (int it = 0; it < 8; ++it) {
                const int idx = tid + (it << 8);
                const int tau = idx >> 10;
                const int rem = idx & 1023;
                const int tl  = rem & (CH - 1);
                const int L2  = rem >> 6;
                const float4* srcp = xv + ((size_t)(rbase + tau * 16 + L2) * T_LEN + CH * ck + tl) * 2;
                const float4 a = srcp[0], b = srcp[1];
                u32x4 u;
                u[0] = pack_bf2(a.x, a.y); u[1] = pack_bf2(a.z, a.w);
                u[2] = pack_bf2(b.x, b.y); u[3] = pack_bf2(b.z, b.w);
                *(u32x4*)(&xl[tau][tl * XSTRIDE + L2 * 8]) = u;
            }
            __syncthreads();   // one-time vm drain per chunk; loop stays vm-free
        }

        const int par = t & 1, nxt = par ^ 1;

        // both tiles' h fragments issued back-to-back (latencies overlap)
        const bf16x8 hfA = *(const bf16x8*)(&h_lds[0][par][hro]);
        const bf16x8 hfB = *(const bf16x8*)(&h_lds[1][par][hro]);

        // on-chain MFMAs, A and B interleaved
        const f32x4 aA0 = __builtin_amdgcn_mfma_f32_16x16x32_bf16(whh[0], hfA, zx[0][0], 0, 0, 0);
        const f32x4 aB0 = __builtin_amdgcn_mfma_f32_16x16x32_bf16(whh[0], hfB, zx[1][0], 0, 0, 0);
        const f32x4 aA1 = __builtin_amdgcn_mfma_f32_16x16x32_bf16(whh[1], hfA, zx[0][1], 0, 0, 0);
        const f32x4 aB1 = __builtin_amdgcn_mfma_f32_16x16x32_bf16(whh[1], hfB, zx[1][1], 0, 0, 0);

        // activations (regs r = i, f, g2, o; g rows pre-doubled):
        // sig(a)*tanh(b) = (1-eb)*rcp((1+ea)(1+eb)); only c-exp clamped.
        const f32x4 accs[2][2] = {{aA0, aA1}, {aB0, aB1}};
#pragma unroll
        for (int tau = 0; tau < 2; ++tau) {
            float hv[2];
#pragma unroll
            for (int e = 0; e < 2; ++e) {
                const f32x4 a = accs[tau][e];
                const float ei = __builtin_amdgcn_exp2f(-a[0]);
                const float ef = __builtin_amdgcn_exp2f(-a[1]);
                const float eg = __builtin_amdgcn_exp2f(-a[2]);
                const float eo = __builtin_amdgcn_exp2f(-a[3]);
                const float fv = __builtin_amdgcn_rcpf(1.f + ef);
                const float ig = (1.f - eg) * __builtin_amdgcn_rcpf((1.f + ei) * (1.f + eg));
                c[tau][e] = fmaf(fv, c[tau][e], ig);
                const float ec = __builtin_amdgcn_exp2f(fminf(c[tau][e] * (-2.f * LOG2E), 40.f));
                hv[e] = (1.f - ec) * __builtin_amdgcn_rcpf((1.f + eo) * (1.f + ec));
            }
            // h(t+1) at (m=L, j=8q+2w / +1): adjacent -> single b32 store
            *(unsigned*)(&h_lds[tau][nxt][hwo]) = pack_bf2(hv[0], hv[1]);
        }

        // off-chain: zx(t+1) for both tiles — issued after the writes,
        // hides in the pre-barrier window
        {
            int tn = t + 1; if (tn >= T_LEN) tn = T_LEN - 1;
            const int xo = (tn & (CH - 1)) * XSTRIDE + L * 8;
            const bf16x8 xfA = *(const bf16x8*)(&xl[0][xo]);
            const bf16x8 xfB = *(const bf16x8*)(&xl[1][xo]);
            zx[0][0] = __builtin_amdgcn_mfma_f32_16x16x32_bf16(wih[0], xfA, bias[0], 0, 0, 0);
            zx[0][1] = __builtin_amdgcn_mfma_f32_16x16x32_bf16(wih[1], xfA, bias[1], 0, 0, 0);
            zx[1][0] = __builtin_amdgcn_mfma_f32_16x16x32_bf16(wih[0], xfB, bias[0], 0, 0, 0);
            zx[1][1] = __builtin_amdgcn_mfma_f32_16x16x32_bf16(wih[1], xfB, bias[1], 0, 0, 0);
        }

        __syncthreads();   // lgkm-only drain (loop is vm-free)
    }

    // h(T) = h(256) lives in buf[0] of each tile
    if (tid < 32) {
        const int tau = tid >> 4, r = tid & 15;
        float s = b_out[0];
#pragma unroll
        for (int k = 0; k < 32; ++k) s = fmaf(bf2f(h_lds[tau][0][r * 40 + k]), W_out[k], s);
        out[rbase + tau * 16 + r] = s;
    }
}

extern "C" void kernel_launch(void* const* d_in, const int* in_sizes, int n_in,
                              void* d_out, int out_size, void* d_ws, size_t ws_size,
                              hipStream_t stream) {
    const float* x     = (const float*)d_in[0];
    const float* W_ih  = (const float*)d_in[1];
    const float* W_hh  = (const float*)d_in[2];
    const float* b_ih  = (const float*)d_in[3];
    const float* b_hh  = (const float*)d_in[4];
    const float* W_out = (const float*)d_in[5];
    const float* b_out = (const float*)d_in[6];
    float* out = (float*)d_out;

    const int B = in_sizes[0] / (T_LEN * 8);  // 4096
    const int blocks = B / 32;                // 128 blocks x 2 tiles
    lstm_kernel<<<blocks, 256, 0, stream>>>(x, W_ih, W_hh, b_ih, b_hh, W_out, b_out, out);
}